// Round 8
// baseline (225.674 us; speedup 1.0000x reference)
//
#include <hip/hip_runtime.h>
#include <hip/hip_bf16.h>
#include <cstdint>
#include <cstddef>

// ---------------------------------------------------------------------------
// GraphHINGE, round 7: gather-BW reduction + w-GEMM fold.
//  conv_emb: emb_user/emb_item f32 -> bf16 tables in ws (halves the dominant
//            gather bytes; attr tables stay f32).
//  fused_all: R6 validated body + phase 5: w[crow] computed in-block from Z
//             (MFMA vs pw1T + tanh + pw2 reduce) -> wbuf.
//  fused_tail: w-GEMM removed (reads wbuf); softmax/pout/MLP unchanged.
// ---------------------------------------------------------------------------

typedef __hip_bfloat16 bf16;
typedef __attribute__((ext_vector_type(8))) short  bfrag;   // 8 bf16 (4 VGPR)
typedef __attribute__((ext_vector_type(4))) float  ffrag;   // 4 f32 acc

__device__ __forceinline__ float bflo(uint32_t u) { return __uint_as_float(u << 16); }
__device__ __forceinline__ float bfhi(uint32_t u) { return __uint_as_float(u & 0xffff0000u); }
__device__ __forceinline__ float bfs(unsigned short s) {
  return __uint_as_float(((uint32_t)s) << 16);
}
__device__ __forceinline__ uint16_t f2bfu(float x) {
  bf16 h = __float2bfloat16(x);
  return *(uint16_t*)&h;
}
__device__ __forceinline__ uint32_t pk2(float lo, float hi) {
  return (uint32_t)f2bfu(lo) | ((uint32_t)f2bfu(hi) << 16);
}

// ---------------- conv: f32 tables -> bf16 (user + item) -------------------
__global__ __launch_bounds__(256) void conv_emb(
    const float* __restrict__ a, const float* __restrict__ b,
    ushort* __restrict__ da, ushort* __restrict__ db, int n4)
{
  int stride = gridDim.x * 256;
  for (int i = blockIdx.x * 256 + threadIdx.x; i < 2 * n4; i += stride) {
    const float4* s; ushort* d; int j;
    if (i < n4) { s = (const float4*)a; d = da; j = i; }
    else        { s = (const float4*)b; d = db; j = i - n4; }
    float4 v = s[j];
    ushort4 o;
    o.x = f2bfu(v.x); o.y = f2bfu(v.y); o.z = f2bfu(v.z); o.w = f2bfu(v.w);
    ((ushort4*)d)[j] = o;
  }
}

// ---------------- merged prep: BmatT + WcT + pw1T --------------------------
// grid 1264: [0,240) BmatT, [240,1200) WcT, [1200,1264) pw1T
__global__ __launch_bounds__(256) void prep_all(
    const float* __restrict__ Ws, const float* __restrict__ Wt,
    const float* __restrict__ Wc, const float* __restrict__ pw1,
    bf16* __restrict__ BmT, bf16* __restrict__ WcT, bf16* __restrict__ pw1T)
{
  int bid = blockIdx.x;
  int tid = threadIdx.x;
  if (bid < 240) {
    int mh = bid >> 4;   // m*3+h
    int g  = bid & 15;
    int m = mh / 3, h = mh % 3;
    const float* ws = Ws + (size_t)mh * 16384;
    const float* wt = Wt + (size_t)mh * 16384;
    int e = tid & 127, half = tid >> 7;
    __shared__ float wtl[2][128];
    for (int ep0 = g * 8; ep0 < g * 8 + 8; ep0 += 2) {
      int ep = ep0 + half;
      wtl[half][e] = wt[ep * 128 + e];
      __syncthreads();
      float acc = 0.f;
      #pragma unroll 4
      for (int o = 0; o < 128; ++o) acc += ws[e * 128 + o] * wtl[half][o];
      BmT[((size_t)(m * 384 + h * 128 + e)) * 128 + ep] = __float2bfloat16(acc);
      __syncthreads();
    }
  } else if (bid < 1200) {
    int idx = (bid - 240) * 256 + tid;   // < 5*128*384
    int he = idx % 384, mo = idx / 384;
    int m = mo >> 7, o = mo & 127;
    WcT[idx] = __float2bfloat16(Wc[((size_t)m * 384 + he) * 128 + o]);
  } else {
    int idx = (bid - 1200) * 256 + tid;  // < 16384
    int o = idx >> 7, k = idx & 127;
    pw1T[idx] = __float2bfloat16(pw1[(size_t)k * 128 + o]);
  }
}

// ---------------- fused per-metapath body (16 nodes, 512 threads) ----------
// UM/TM: bit p set = table p is f32 (else bf16 ushort)
template <int P, int UM, int TM>
__device__ __forceinline__ void metapath_body(
    char* smem,
    const void* Tu0, const void* Tu1, const void* Tu2, const void* Tu3,
    const void* Tt0, const void* Tt1, const void* Tt2, const void* Tt3,
    const int* __restrict__ idxU, const int* __restrict__ idxT,
    const bf16* __restrict__ BmT,    // [384][128] (this metapath)
    const bf16* __restrict__ WcT,    // [128][384]
    const bf16* __restrict__ pw1T,   // [128][128] (o-major)
    const float* __restrict__ pb1, const float* __restrict__ pw2,
    bf16* __restrict__ Zall, float* __restrict__ wbuf, int m, int tile)
{
  constexpr int PP = 2 * P - 1;
  constexpr int NS = PP * 136;       // node stride in Hs (bf16)
  bf16* Hs = (bf16*)smem;                          // [16][PP][136]
  bf16* Ss = Hs + 16 * NS;                         // [16][392] (S, then Hbar)
  bf16* Al = Ss + 16 * 392;                        // [16][3][8] alpha
  float* wred = (float*)(Al + 16 * 24);            // [8][16]

  int tid = threadIdx.x;
  int lane = tid & 63, wid = tid >> 6;
  int l15 = lane & 15, l4 = lane >> 4;
  int n0 = tile * 16;

  // ---- phase 1: gather (all loads hoisted) + cross-correlate -> Hs ----
  {
    const void* TU[4] = {Tu0, Tu1, Tu2, Tu3};
    const void* TT[4] = {Tt0, Tt1, Tt2, Tt3};
    int e = tid & 127;
    float su[4][P], st[4][P];
    #pragma unroll
    for (int g = 0; g < 4; ++g) {
      int n = n0 + g * 4 + (tid >> 7);
      #pragma unroll
      for (int p = 0; p < P; ++p) {
        size_t ou = (size_t)idxU[n * P + p] * 128 + e;
        size_t ot = (size_t)idxT[n * P + p] * 128 + e;
        su[g][p] = ((UM >> p) & 1) ? ((const float*)TU[p])[ou]
                                   : bfs(((const ushort*)TU[p])[ou]);
        st[g][p] = ((TM >> p) & 1) ? ((const float*)TT[p])[ot]
                                   : bfs(((const ushort*)TT[p])[ot]);
      }
    }
    #pragma unroll
    for (int g = 0; g < 4; ++g) {
      int ln = g * 4 + (tid >> 7);
      bf16* Hn = &Hs[ln * NS + e];
      #pragma unroll
      for (int k = 0; k < PP; ++k) {
        float acc = 0.f;
        #pragma unroll
        for (int i = 0; i < P; ++i) {
          int j = k + i - (P - 1);
          if (j >= 0 && j < P) acc += su[g][j] * st[g][i];
        }
        Hn[k * 136] = __float2bfloat16(acc);
      }
    }
  }
  __syncthreads();

  // ---- phase 2: S = H0 @ BmatT : M=16, N=384, K=128 (8 waves x 3 frags) ---
  {
    bfrag a[4];
    #pragma unroll
    for (int kk = 0; kk < 4; ++kk)
      a[kk] = *(const bfrag*)&Hs[l15 * NS + kk * 32 + 8 * l4];   // H0 row
    #pragma unroll
    for (int f = 0; f < 3; ++f) {
      int col = wid * 48 + f * 16 + l15;
      ffrag acc = {0.f, 0.f, 0.f, 0.f};
      #pragma unroll
      for (int kk = 0; kk < 4; ++kk) {
        bfrag b = *(const bfrag*)&BmT[(size_t)col * 128 + kk * 32 + 8 * l4];
        acc = __builtin_amdgcn_mfma_f32_16x16x32_bf16(a[kk], b, acc, 0, 0, 0);
      }
      #pragma unroll
      for (int r = 0; r < 4; ++r) {
        int node = 4 * l4 + r;
        Ss[node * 392 + col] = __float2bfloat16(acc[r]);
      }
    }
  }
  __syncthreads();

  // ---- phase 3: logits (MFMA, 2 nodes/wave) -> butterfly softmax ->
  //      alpha(LDS) -> Hbar (static VALU). All within-wave, no barriers. ----
  {
    int nd0 = wid * 2, nd1 = nd0 + 1;
    bool hi = (l15 >= 8);
    int nodeA = hi ? nd1 : nd0;
    int r15 = hi ? (l15 - 8) : l15;               // 0..7
    int ah = (r15 < 3) ? r15 : 2;                 // junk-row clamp
    int bp = (r15 < PP) ? r15 : (PP - 1);         // junk-col clamp
    ffrag lacc = {0.f, 0.f, 0.f, 0.f};
    #pragma unroll
    for (int kk = 0; kk < 4; ++kk) {
      bfrag av = *(const bfrag*)&Ss[nodeA * 392 + ah * 128 + kk * 32 + 8 * l4];
      bfrag bv = *(const bfrag*)&Hs[nodeA * NS + bp * 136 + kk * 32 + 8 * l4];
      lacc = __builtin_amdgcn_mfma_f32_16x16x32_bf16(av, bv, lacc, 0, 0, 0);
    }
    bool val = ((l4 == 0) && !hi && (l15 < PP)) ||
               ((l4 == 2) &&  hi && (r15 < PP));
    float lg0 = val ? lacc[0] * 5.0f : -1e30f;    // /T1
    float lg1 = val ? lacc[1] * 5.0f : -1e30f;
    float lg2 = val ? lacc[2] * 5.0f : -1e30f;
    float m0 = lg0, m1 = lg1, m2 = lg2;
    #pragma unroll
    for (int d = 1; d < 8; d <<= 1) {
      m0 = fmaxf(m0, __shfl_xor(m0, d));
      m1 = fmaxf(m1, __shfl_xor(m1, d));
      m2 = fmaxf(m2, __shfl_xor(m2, d));
    }
    float e0 = val ? __expf(lg0 - m0) : 0.f;
    float e1 = val ? __expf(lg1 - m1) : 0.f;
    float e2 = val ? __expf(lg2 - m2) : 0.f;
    float s0 = e0, s1 = e1, s2 = e2;
    #pragma unroll
    for (int d = 1; d < 8; d <<= 1) {
      s0 += __shfl_xor(s0, d);
      s1 += __shfl_xor(s1, d);
      s2 += __shfl_xor(s2, d);
    }
    if (val) {
      bf16* Aln = Al + nodeA * 24;
      Aln[r15]      = __float2bfloat16(e0 / s0);
      Aln[8 + r15]  = __float2bfloat16(e1 / s1);
      Aln[16 + r15] = __float2bfloat16(e2 / s2);
    }

    // Hbar[node][h*128+e] = sum_p alpha[h][p] * H[p][e]
    int node = tid >> 5, q = tid & 31;
    bfrag al0 = *(const bfrag*)&Al[node * 24];
    bfrag al1 = *(const bfrag*)&Al[node * 24 + 8];
    bfrag al2 = *(const bfrag*)&Al[node * 24 + 16];
    #pragma unroll
    for (int j = 0; j < 2; ++j) {
      int e2i = 4 * q + 2 * j;
      float a00 = 0.f, a01 = 0.f, a10 = 0.f, a11 = 0.f, a20 = 0.f, a21 = 0.f;
      #pragma unroll
      for (int pp = 0; pp < PP; ++pp) {
        uint32_t hv = *(const uint32_t*)&Hs[node * NS + pp * 136 + e2i];
        float lo = bflo(hv), hh = bfhi(hv);
        float f0 = bfs((unsigned short)al0[pp]);
        float f1 = bfs((unsigned short)al1[pp]);
        float f2 = bfs((unsigned short)al2[pp]);
        a00 += f0 * lo; a01 += f0 * hh;
        a10 += f1 * lo; a11 += f1 * hh;
        a20 += f2 * lo; a21 += f2 * hh;
      }
      *(uint32_t*)&Ss[node * 392 +       e2i] = pk2(a00, a01);
      *(uint32_t*)&Ss[node * 392 + 128 + e2i] = pk2(a10, a11);
      *(uint32_t*)&Ss[node * 392 + 256 + e2i] = pk2(a20, a21);
    }
  }
  __syncthreads();

  // ---- phase 4: Z = Hbar @ WcT / 3, write Zall + stage Z in LDS ----------
  bf16* Zs = Hs;   // Hs free after phase 3
  {
    bfrag a[12];
    #pragma unroll
    for (int kk = 0; kk < 12; ++kk)
      a[kk] = *(const bfrag*)&Ss[l15 * 392 + kk * 32 + 8 * l4];
    int col = wid * 16 + l15;
    ffrag acc = {0.f, 0.f, 0.f, 0.f};
    #pragma unroll
    for (int kk = 0; kk < 12; ++kk) {
      bfrag b = *(const bfrag*)&WcT[(size_t)col * 384 + kk * 32 + 8 * l4];
      acc = __builtin_amdgcn_mfma_f32_16x16x32_bf16(a[kk], b, acc, 0, 0, 0);
    }
    #pragma unroll
    for (int r = 0; r < 4; ++r) {
      int node = 4 * l4 + r;
      int gn = n0 + node;
      int crow = (((gn >> 5) * 5 + m) << 5) + (gn & 31);
      bf16 zb = __float2bfloat16(acc[r] * (1.0f / 3.0f));
      Zall[(size_t)crow * 128 + col] = zb;
      Zs[node * 136 + col] = zb;
    }
  }
  __syncthreads();

  // ---- phase 5: w[node] = 5 * sum_col tanh((Z@pw1)[col]+pb1)*pw2 ---------
  {
    bfrag a5[4];
    #pragma unroll
    for (int kk = 0; kk < 4; ++kk)
      a5[kk] = *(const bfrag*)&Zs[l15 * 136 + kk * 32 + 8 * l4];
    int col = wid * 16 + l15;
    ffrag acc5 = {0.f, 0.f, 0.f, 0.f};
    #pragma unroll
    for (int kk = 0; kk < 4; ++kk) {
      bfrag b = *(const bfrag*)&pw1T[(size_t)col * 128 + kk * 32 + 8 * l4];
      acc5 = __builtin_amdgcn_mfma_f32_16x16x32_bf16(a5[kk], b, acc5, 0, 0, 0);
    }
    float bias = pb1[col], w2 = pw2[col];
    float part[4];
    #pragma unroll
    for (int r = 0; r < 4; ++r) part[r] = tanhf(acc5[r] + bias) * w2;
    #pragma unroll
    for (int d = 1; d < 16; d <<= 1) {
      #pragma unroll
      for (int r = 0; r < 4; ++r) part[r] += __shfl_xor(part[r], d);
    }
    if (l15 == 0) {
      #pragma unroll
      for (int r = 0; r < 4; ++r) wred[wid * 16 + 4 * l4 + r] = part[r];
    }
  }
  __syncthreads();
  if (tid < 16) {
    float s = 0.f;
    #pragma unroll
    for (int w = 0; w < 8; ++w) s += wred[w * 16 + tid];
    int gn = n0 + tid;
    int crow = (((gn >> 5) * 5 + m) << 5) + (gn & 31);
    wbuf[crow] = s * 5.0f;   // /T2
  }
}

// ---------------- all 5 metapaths in one launch ----------------------------
// grid = 5120: bid>>10 = m, bid&1023 = tile
__global__ __launch_bounds__(512) void fused_all(
    const ushort* __restrict__ EU, const ushort* __restrict__ EI,
    const float* __restrict__ emb_a1, const float* __restrict__ emb_a2,
    const float* __restrict__ emb_a3,
    const int* __restrict__ UI,    const int* __restrict__ IU,
    const int* __restrict__ UIUI,  const int* __restrict__ IUIU,
    const int* __restrict__ UIAI1, const int* __restrict__ IAIU1,
    const int* __restrict__ UIAI2, const int* __restrict__ IAIU2,
    const int* __restrict__ UIAI3, const int* __restrict__ IAIU3,
    const bf16* __restrict__ BmT, const bf16* __restrict__ WcT,
    const bf16* __restrict__ pw1T,
    const float* __restrict__ pb1, const float* __restrict__ pw2,
    bf16* __restrict__ Zall, float* __restrict__ wbuf)
{
  extern __shared__ char smem[];
  int bid = blockIdx.x;
  int m = bid >> 10, tile = bid & 1023;
  if (m == 0) {
    metapath_body<2, 0, 0>(smem, EU, EI, nullptr, nullptr,
                           EI, EU, nullptr, nullptr,
                           UI, IU, BmT, WcT, pw1T, pb1, pw2,
                           Zall, wbuf, 0, tile);
  } else if (m == 1) {
    metapath_body<4, 0, 0>(smem, EU, EI, EU, EI,
                           EI, EU, EI, EU,
                           UIUI, IUIU,
                           BmT + (size_t)1 * 49152, WcT + (size_t)1 * 49152,
                           pw1T, pb1, pw2, Zall, wbuf, 1, tile);
  } else {
    const float* at = (m == 2) ? emb_a1 : (m == 3) ? emb_a2 : emb_a3;
    const int* iu_ = (m == 2) ? UIAI1 : (m == 3) ? UIAI2 : UIAI3;
    const int* it_ = (m == 2) ? IAIU1 : (m == 3) ? IAIU2 : IAIU3;
    metapath_body<4, 4, 2>(smem, EU, EI, at, EI,
                           EI, at, EI, EU,
                           iu_, it_,
                           BmT + (size_t)m * 49152, WcT + (size_t)m * 49152,
                           pw1T, pb1, pw2, Zall, wbuf, m, tile);
  }
}

// ---------------- fused tail: beta softmax + pout + final MLP --------------
// block = 1 batch element b, 512 threads (8 waves); grid = 512
__global__ __launch_bounds__(512) void fused_tail(
    const bf16* __restrict__ Zall,    // [512*160][128], row b*160+j
    const float* __restrict__ wbuf,   // [512*160]
    const int* __restrict__ UI, const int* __restrict__ IU,
    const float* __restrict__ emb_user, const float* __restrict__ emb_item,
    const float* __restrict__ fw1, const float* __restrict__ fb1,
    const float* __restrict__ fw2, const float* __restrict__ fb2,
    float* __restrict__ out)
{
  __shared__ bf16 Zs[160 * 136];
  __shared__ float wrow[160];
  __shared__ float ph[4][128];
  __shared__ float xs[384];
  __shared__ float sred[16];
  __shared__ float yred[2];

  int b = blockIdx.x, tid = threadIdx.x;
  int lane = tid & 63, wid = tid >> 6;

  // ---- stage z-block (160x128 bf16) -> LDS, raw 16B copies, hoisted ----
  {
    const float4* src = (const float4*)(Zall + (size_t)b * 160 * 128);
    float4 v[5];
    #pragma unroll
    for (int i = 0; i < 5; ++i) v[i] = src[i * 512 + tid];
    if (tid < 160) wrow[tid] = wbuf[b * 160 + tid];
    #pragma unroll
    for (int i = 0; i < 5; ++i) {
      int idx = i * 512 + tid;            // 0..2559
      int row = idx >> 4, c8 = idx & 15;
      *(float4*)&Zs[row * 136 + c8 * 8] = v[i];
    }
  }
  __syncthreads();

  // ---- softmax over 160 paths (wave-parallel) ----
  {
    float v = (tid < 160) ? wrow[tid] : -1e30f;
    #pragma unroll
    for (int off = 32; off; off >>= 1) v = fmaxf(v, __shfl_xor(v, off));
    if (lane == 0) sred[wid] = v;
    __syncthreads();
    if (tid < 64) {
      float mval = (lane < 8) ? sred[lane] : -1e30f;
      #pragma unroll
      for (int off = 4; off; off >>= 1) mval = fmaxf(mval, __shfl_xor(mval, off));
      if (lane == 0) sred[8] = mval;
    }
    __syncthreads();
    float mx = sred[8];
    float ev = (tid < 160) ? __expf(wrow[tid] - mx) : 0.f;
    float s = ev;
    #pragma unroll
    for (int off = 32; off; off >>= 1) s += __shfl_xor(s, off);
    if (lane == 0) sred[wid] = s;
    __syncthreads();
    if (tid < 64) {
      float sval = (lane < 8) ? sred[lane] : 0.f;
      #pragma unroll
      for (int off = 4; off; off >>= 1) sval += __shfl_xor(sval, off);
      if (lane == 0) sred[9] = sval;
    }
    __syncthreads();
    if (tid < 160) wrow[tid] = ev / sred[9];
  }
  __syncthreads();

  // ---- pout[e] = sum_j beta[j]*z[j][e]  (4-way split over j) ----
  {
    int e = tid & 127, q = tid >> 7;
    float acc = 0.f;
    #pragma unroll 4
    for (int j = q * 40; j < q * 40 + 40; ++j)
      acc += wrow[j] * __bfloat162float(Zs[j * 136 + e]);
    ph[q][e] = acc;
  }
  __syncthreads();

  // ---- build x = [src_emb, tgt_emb, pout] ----
  {
    int su = UI[b * 64];   // UI[b][0][0]
    int ti = IU[b * 64];   // IU[b][0][0]
    if (tid < 128) {
      xs[256 + tid] = ph[0][tid] + ph[1][tid] + ph[2][tid] + ph[3][tid];
    } else if (tid < 256) {
      xs[tid - 128] = emb_user[(size_t)su * 128 + (tid - 128)];
    } else if (tid < 384) {
      xs[tid - 128] = emb_item[(size_t)ti * 128 + (tid - 256)];
    }
  }
  __syncthreads();

  // ---- final: y = relu(x@fw1+fb1); out = sigmoid(y.fw2+fb2) ----
  {
    int o = tid & 127, q = tid >> 7;
    float acc = 0.f;
    #pragma unroll 4
    for (int i = q * 96; i < q * 96 + 96; ++i)
      acc += xs[i] * fw1[(size_t)i * 128 + o];
    __syncthreads();          // ph free now
    ph[q][o] = acc;
  }
  __syncthreads();
  if (tid < 128) {
    float y = fmaxf(ph[0][tid] + ph[1][tid] + ph[2][tid] + ph[3][tid] + fb1[tid],
                    0.0f) * fw2[tid];
    #pragma unroll
    for (int off = 32; off; off >>= 1) y += __shfl_down(y, off);
    if ((tid & 63) == 0) yred[tid >> 6] = y;
  }
  __syncthreads();
  if (tid == 0) {
    float s = yred[0] + yred[1] + fb2[0];
    out[b] = 1.0f / (1.0f + expf(-s));
  }
}

// ---------------------------------------------------------------------------
extern "C" void kernel_launch(void* const* d_in, const int* in_sizes, int n_in,
                              void* d_out, int out_size, void* d_ws, size_t ws_size,
                              hipStream_t stream)
{
  const int* UI    = (const int*)d_in[0];
  const int* IU    = (const int*)d_in[1];
  const int* UIUI  = (const int*)d_in[2];
  const int* IUIU  = (const int*)d_in[3];
  const int* UIAI1 = (const int*)d_in[4];
  const int* IAIU1 = (const int*)d_in[5];
  const int* UIAI2 = (const int*)d_in[6];
  const int* IAIU2 = (const int*)d_in[7];
  const int* UIAI3 = (const int*)d_in[8];
  const int* IAIU3 = (const int*)d_in[9];
  const float* emb_user = (const float*)d_in[10];
  const float* emb_item = (const float*)d_in[11];
  const float* emb_a1   = (const float*)d_in[12];
  const float* emb_a2   = (const float*)d_in[13];
  const float* emb_a3   = (const float*)d_in[14];
  const float* Wt  = (const float*)d_in[15];
  const float* Ws  = (const float*)d_in[16];
  const float* Wc  = (const float*)d_in[17];
  const float* pw1 = (const float*)d_in[18];
  const float* pb1 = (const float*)d_in[19];
  const float* pw2 = (const float*)d_in[20];
  const float* fw1 = (const float*)d_in[21];
  const float* fb1 = (const float*)d_in[22];
  const float* fw2 = (const float*)d_in[23];
  const float* fb2 = (const float*)d_in[24];
  float* out = (float*)d_out;

  // ---- workspace carve (bytes) ----
  char* wsb = (char*)d_ws;
  bf16*   BmT  = (bf16*)wsb;                          // 491,520 B
  bf16*   WcT  = (bf16*)(wsb + 491520);               // 491,520 B
  bf16*   pw1T = (bf16*)(wsb + 983040);               //  32,768 B
  bf16*   Zall = (bf16*)(wsb + 1015808);              // 20,971,520 B
  float*  wbuf = (float*)(wsb + 21987328);            //    327,680 B
  ushort* EU16 = (ushort*)(wsb + 22315008);           // 25,600,256 B
  ushort* EI16 = (ushort*)(wsb + 47915264);           // 25,600,256 B
  // end: 73,515,520 B

  int n4 = (100001 * 128) / 4;   // 3,200,032 float4s per table
  conv_emb<<<8192, 256, 0, stream>>>(emb_user, emb_item, EU16, EI16, n4);
  prep_all<<<1264, 256, 0, stream>>>(Ws, Wt, Wc, pw1, BmT, WcT, pw1T);

  // dyn LDS (PP=7): Hs 30464 + Ss 12544 + Al 768 + wred 512 = 44288 B
  fused_all<<<5120, 512, 44288, stream>>>(
      EU16, EI16, emb_a1, emb_a2, emb_a3,
      UI, IU, UIUI, IUIU, UIAI1, IAIU1, UIAI2, IAIU2, UIAI3, IAIU3,
      BmT, WcT, pw1T, pb1, pw2, Zall, wbuf);

  fused_tail<<<512, 512, 0, stream>>>(Zall, wbuf,
                                      UI, IU, emb_user, emb_item,
                                      fw1, fb1, fw2, fb2, out);
}

// Round 9
// 214.995 us; speedup vs baseline: 1.0497x; 1.0497x over previous
//
#include <hip/hip_runtime.h>
#include <hip/hip_bf16.h>
#include <cstdint>
#include <cstddef>

// ---------------------------------------------------------------------------
// GraphHINGE, round 8: 2-tile software pipeline inside fused_all.
//  Each block handles 2 tiles: gather T0 -> corr T0 -> ISSUE T1 gather (raw
//  bits held in VGPRs) -> compute T0 (phases 2-5) -> corr T1 (loads already
//  landed) -> compute T1. Gather latency of odd tiles hides under even tiles'
//  compute. Body of phases 2-5 identical to validated round 7.
// ---------------------------------------------------------------------------

typedef __hip_bfloat16 bf16;
typedef __attribute__((ext_vector_type(8))) short  bfrag;   // 8 bf16 (4 VGPR)
typedef __attribute__((ext_vector_type(4))) float  ffrag;   // 4 f32 acc

__device__ __forceinline__ float bflo(uint32_t u) { return __uint_as_float(u << 16); }
__device__ __forceinline__ float bfhi(uint32_t u) { return __uint_as_float(u & 0xffff0000u); }
__device__ __forceinline__ float bfs(unsigned short s) {
  return __uint_as_float(((uint32_t)s) << 16);
}
__device__ __forceinline__ uint16_t f2bfu(float x) {
  bf16 h = __float2bfloat16(x);
  return *(uint16_t*)&h;
}
__device__ __forceinline__ uint32_t pk2(float lo, float hi) {
  return (uint32_t)f2bfu(lo) | ((uint32_t)f2bfu(hi) << 16);
}

// ---------------- conv: f32 tables -> bf16 (user + item) -------------------
__global__ __launch_bounds__(256) void conv_emb(
    const float* __restrict__ a, const float* __restrict__ b,
    ushort* __restrict__ da, ushort* __restrict__ db, int n4)
{
  int stride = gridDim.x * 256;
  for (int i = blockIdx.x * 256 + threadIdx.x; i < 2 * n4; i += stride) {
    const float4* s; ushort* d; int j;
    if (i < n4) { s = (const float4*)a; d = da; j = i; }
    else        { s = (const float4*)b; d = db; j = i - n4; }
    float4 v = s[j];
    ushort4 o;
    o.x = f2bfu(v.x); o.y = f2bfu(v.y); o.z = f2bfu(v.z); o.w = f2bfu(v.w);
    ((ushort4*)d)[j] = o;
  }
}

// ---------------- merged prep: BmatT + WcT + pw1T --------------------------
__global__ __launch_bounds__(256) void prep_all(
    const float* __restrict__ Ws, const float* __restrict__ Wt,
    const float* __restrict__ Wc, const float* __restrict__ pw1,
    bf16* __restrict__ BmT, bf16* __restrict__ WcT, bf16* __restrict__ pw1T)
{
  int bid = blockIdx.x;
  int tid = threadIdx.x;
  if (bid < 240) {
    int mh = bid >> 4;   // m*3+h
    int g  = bid & 15;
    int m = mh / 3, h = mh % 3;
    const float* ws = Ws + (size_t)mh * 16384;
    const float* wt = Wt + (size_t)mh * 16384;
    int e = tid & 127, half = tid >> 7;
    __shared__ float wtl[2][128];
    for (int ep0 = g * 8; ep0 < g * 8 + 8; ep0 += 2) {
      int ep = ep0 + half;
      wtl[half][e] = wt[ep * 128 + e];
      __syncthreads();
      float acc = 0.f;
      #pragma unroll 4
      for (int o = 0; o < 128; ++o) acc += ws[e * 128 + o] * wtl[half][o];
      BmT[((size_t)(m * 384 + h * 128 + e)) * 128 + ep] = __float2bfloat16(acc);
      __syncthreads();
    }
  } else if (bid < 1200) {
    int idx = (bid - 240) * 256 + tid;   // < 5*128*384
    int he = idx % 384, mo = idx / 384;
    int m = mo >> 7, o = mo & 127;
    WcT[idx] = __float2bfloat16(Wc[((size_t)m * 384 + he) * 128 + o]);
  } else {
    int idx = (bid - 1200) * 256 + tid;  // < 16384
    int o = idx >> 7, k = idx & 127;
    pw1T[idx] = __float2bfloat16(pw1[(size_t)k * 128 + o]);
  }
}

// ---------------- gather issue: raw bits into VGPRs (no dependent cvt) -----
template <int P, int UM, int TM>
__device__ __forceinline__ void gather_issue(
    const void* const* TU, const void* const* TT,
    const int* __restrict__ idxU, const int* __restrict__ idxT,
    int n0, int tid, uint32_t (&su)[4][P], uint32_t (&st)[4][P])
{
  int e = tid & 127;
  #pragma unroll
  for (int g = 0; g < 4; ++g) {
    int n = n0 + g * 4 + (tid >> 7);
    #pragma unroll
    for (int p = 0; p < P; ++p) {
      size_t ou = (size_t)idxU[n * P + p] * 128 + e;
      size_t ot = (size_t)idxT[n * P + p] * 128 + e;
      su[g][p] = ((UM >> p) & 1) ? __float_as_uint(((const float*)TU[p])[ou])
                                 : (uint32_t)((const ushort*)TU[p])[ou];
      st[g][p] = ((TM >> p) & 1) ? __float_as_uint(((const float*)TT[p])[ot])
                                 : (uint32_t)((const ushort*)TT[p])[ot];
    }
  }
}

// ---------------- corr: raw regs -> Hs rows --------------------------------
template <int P, int UM, int TM>
__device__ __forceinline__ void corr_store(
    bf16* __restrict__ Hs, const uint32_t (&su)[4][P],
    const uint32_t (&st)[4][P], int tid)
{
  constexpr int PP = 2 * P - 1;
  constexpr int NS = PP * 136;
  int e = tid & 127;
  #pragma unroll
  for (int g = 0; g < 4; ++g) {
    int ln = g * 4 + (tid >> 7);
    float fu[P], ft[P];
    #pragma unroll
    for (int p = 0; p < P; ++p) {
      fu[p] = ((UM >> p) & 1) ? __uint_as_float(su[g][p])
                              : __uint_as_float(su[g][p] << 16);
      ft[p] = ((TM >> p) & 1) ? __uint_as_float(st[g][p])
                              : __uint_as_float(st[g][p] << 16);
    }
    bf16* Hn = &Hs[ln * NS + e];
    #pragma unroll
    for (int k = 0; k < PP; ++k) {
      float acc = 0.f;
      #pragma unroll
      for (int i = 0; i < P; ++i) {
        int j = k + i - (P - 1);
        if (j >= 0 && j < P) acc += fu[j] * ft[i];
      }
      Hn[k * 136] = __float2bfloat16(acc);
    }
  }
}

// ---------------- compute phases 2-5 for one staged tile (R7 body) ---------
template <int P>
__device__ __forceinline__ void compute_tile(
    char* smem,
    const bf16* __restrict__ BmT, const bf16* __restrict__ WcT,
    const bf16* __restrict__ pw1T,
    const float* __restrict__ pb1, const float* __restrict__ pw2,
    bf16* __restrict__ Zall, float* __restrict__ wbuf, int m, int tile)
{
  constexpr int PP = 2 * P - 1;
  constexpr int NS = PP * 136;
  bf16* Hs = (bf16*)smem;                          // [16][PP][136]
  bf16* Ss = Hs + 16 * NS;                         // [16][392]
  bf16* Al = Ss + 16 * 392;                        // [16][3][8]
  float* wred = (float*)(Al + 16 * 24);            // [8][16]

  int tid = threadIdx.x;
  int lane = tid & 63, wid = tid >> 6;
  int l15 = lane & 15, l4 = lane >> 4;
  int n0 = tile * 16;

  // ---- phase 2: S = H0 @ BmatT ----
  {
    bfrag a[4];
    #pragma unroll
    for (int kk = 0; kk < 4; ++kk)
      a[kk] = *(const bfrag*)&Hs[l15 * NS + kk * 32 + 8 * l4];
    #pragma unroll
    for (int f = 0; f < 3; ++f) {
      int col = wid * 48 + f * 16 + l15;
      ffrag acc = {0.f, 0.f, 0.f, 0.f};
      #pragma unroll
      for (int kk = 0; kk < 4; ++kk) {
        bfrag b = *(const bfrag*)&BmT[(size_t)col * 128 + kk * 32 + 8 * l4];
        acc = __builtin_amdgcn_mfma_f32_16x16x32_bf16(a[kk], b, acc, 0, 0, 0);
      }
      #pragma unroll
      for (int r = 0; r < 4; ++r) {
        int node = 4 * l4 + r;
        Ss[node * 392 + col] = __float2bfloat16(acc[r]);
      }
    }
  }
  __syncthreads();

  // ---- phase 3: logits (MFMA) -> butterfly softmax -> alpha -> Hbar ----
  {
    int nd0 = wid * 2, nd1 = nd0 + 1;
    bool hi = (l15 >= 8);
    int nodeA = hi ? nd1 : nd0;
    int r15 = hi ? (l15 - 8) : l15;
    int ah = (r15 < 3) ? r15 : 2;
    int bp = (r15 < PP) ? r15 : (PP - 1);
    ffrag lacc = {0.f, 0.f, 0.f, 0.f};
    #pragma unroll
    for (int kk = 0; kk < 4; ++kk) {
      bfrag av = *(const bfrag*)&Ss[nodeA * 392 + ah * 128 + kk * 32 + 8 * l4];
      bfrag bv = *(const bfrag*)&Hs[nodeA * NS + bp * 136 + kk * 32 + 8 * l4];
      lacc = __builtin_amdgcn_mfma_f32_16x16x32_bf16(av, bv, lacc, 0, 0, 0);
    }
    bool val = ((l4 == 0) && !hi && (l15 < PP)) ||
               ((l4 == 2) &&  hi && (r15 < PP));
    float lg0 = val ? lacc[0] * 5.0f : -1e30f;    // /T1
    float lg1 = val ? lacc[1] * 5.0f : -1e30f;
    float lg2 = val ? lacc[2] * 5.0f : -1e30f;
    float m0 = lg0, m1 = lg1, m2 = lg2;
    #pragma unroll
    for (int d = 1; d < 8; d <<= 1) {
      m0 = fmaxf(m0, __shfl_xor(m0, d));
      m1 = fmaxf(m1, __shfl_xor(m1, d));
      m2 = fmaxf(m2, __shfl_xor(m2, d));
    }
    float e0 = val ? __expf(lg0 - m0) : 0.f;
    float e1 = val ? __expf(lg1 - m1) : 0.f;
    float e2 = val ? __expf(lg2 - m2) : 0.f;
    float s0 = e0, s1 = e1, s2 = e2;
    #pragma unroll
    for (int d = 1; d < 8; d <<= 1) {
      s0 += __shfl_xor(s0, d);
      s1 += __shfl_xor(s1, d);
      s2 += __shfl_xor(s2, d);
    }
    if (val) {
      bf16* Aln = Al + nodeA * 24;
      Aln[r15]      = __float2bfloat16(e0 / s0);
      Aln[8 + r15]  = __float2bfloat16(e1 / s1);
      Aln[16 + r15] = __float2bfloat16(e2 / s2);
    }

    int node = tid >> 5, q = tid & 31;
    bfrag al0 = *(const bfrag*)&Al[node * 24];
    bfrag al1 = *(const bfrag*)&Al[node * 24 + 8];
    bfrag al2 = *(const bfrag*)&Al[node * 24 + 16];
    #pragma unroll
    for (int j = 0; j < 2; ++j) {
      int e2i = 4 * q + 2 * j;
      float a00 = 0.f, a01 = 0.f, a10 = 0.f, a11 = 0.f, a20 = 0.f, a21 = 0.f;
      #pragma unroll
      for (int pp = 0; pp < PP; ++pp) {
        uint32_t hv = *(const uint32_t*)&Hs[node * NS + pp * 136 + e2i];
        float lo = bflo(hv), hh = bfhi(hv);
        float f0 = bfs((unsigned short)al0[pp]);
        float f1 = bfs((unsigned short)al1[pp]);
        float f2 = bfs((unsigned short)al2[pp]);
        a00 += f0 * lo; a01 += f0 * hh;
        a10 += f1 * lo; a11 += f1 * hh;
        a20 += f2 * lo; a21 += f2 * hh;
      }
      *(uint32_t*)&Ss[node * 392 +       e2i] = pk2(a00, a01);
      *(uint32_t*)&Ss[node * 392 + 128 + e2i] = pk2(a10, a11);
      *(uint32_t*)&Ss[node * 392 + 256 + e2i] = pk2(a20, a21);
    }
  }
  __syncthreads();

  // ---- phase 4: Z = Hbar @ WcT / 3, write Zall + stage Z in LDS ----
  bf16* Zs = Hs;
  {
    bfrag a[12];
    #pragma unroll
    for (int kk = 0; kk < 12; ++kk)
      a[kk] = *(const bfrag*)&Ss[l15 * 392 + kk * 32 + 8 * l4];
    int col = wid * 16 + l15;
    ffrag acc = {0.f, 0.f, 0.f, 0.f};
    #pragma unroll
    for (int kk = 0; kk < 12; ++kk) {
      bfrag b = *(const bfrag*)&WcT[(size_t)col * 384 + kk * 32 + 8 * l4];
      acc = __builtin_amdgcn_mfma_f32_16x16x32_bf16(a[kk], b, acc, 0, 0, 0);
    }
    #pragma unroll
    for (int r = 0; r < 4; ++r) {
      int node = 4 * l4 + r;
      int gn = n0 + node;
      int crow = (((gn >> 5) * 5 + m) << 5) + (gn & 31);
      bf16 zb = __float2bfloat16(acc[r] * (1.0f / 3.0f));
      Zall[(size_t)crow * 128 + col] = zb;
      Zs[node * 136 + col] = zb;
    }
  }
  __syncthreads();

  // ---- phase 5: w[node] = 5 * sum_col tanh((Z@pw1)[col]+pb1)*pw2 ----
  {
    bfrag a5[4];
    #pragma unroll
    for (int kk = 0; kk < 4; ++kk)
      a5[kk] = *(const bfrag*)&Zs[l15 * 136 + kk * 32 + 8 * l4];
    int col = wid * 16 + l15;
    ffrag acc5 = {0.f, 0.f, 0.f, 0.f};
    #pragma unroll
    for (int kk = 0; kk < 4; ++kk) {
      bfrag b = *(const bfrag*)&pw1T[(size_t)col * 128 + kk * 32 + 8 * l4];
      acc5 = __builtin_amdgcn_mfma_f32_16x16x32_bf16(a5[kk], b, acc5, 0, 0, 0);
    }
    float bias = pb1[col], w2 = pw2[col];
    float part[4];
    #pragma unroll
    for (int r = 0; r < 4; ++r) part[r] = tanhf(acc5[r] + bias) * w2;
    #pragma unroll
    for (int d = 1; d < 16; d <<= 1) {
      #pragma unroll
      for (int r = 0; r < 4; ++r) part[r] += __shfl_xor(part[r], d);
    }
    if (l15 == 0) {
      #pragma unroll
      for (int r = 0; r < 4; ++r) wred[wid * 16 + 4 * l4 + r] = part[r];
    }
  }
  __syncthreads();
  if (tid < 16) {
    float s = 0.f;
    #pragma unroll
    for (int w = 0; w < 8; ++w) s += wred[w * 16 + tid];
    int gn = n0 + tid;
    int crow = (((gn >> 5) * 5 + m) << 5) + (gn & 31);
    wbuf[crow] = s * 5.0f;   // /T2
  }
}

// ---------------- 2-tile pipelined body ------------------------------------
template <int P, int UM, int TM>
__device__ __forceinline__ void pipeline_body(
    char* smem,
    const void* Tu0, const void* Tu1, const void* Tu2, const void* Tu3,
    const void* Tt0, const void* Tt1, const void* Tt2, const void* Tt3,
    const int* __restrict__ idxU, const int* __restrict__ idxT,
    const bf16* __restrict__ BmT, const bf16* __restrict__ WcT,
    const bf16* __restrict__ pw1T,
    const float* __restrict__ pb1, const float* __restrict__ pw2,
    bf16* __restrict__ Zall, float* __restrict__ wbuf, int m, int pair)
{
  const void* TU[4] = {Tu0, Tu1, Tu2, Tu3};
  const void* TT[4] = {Tt0, Tt1, Tt2, Tt3};
  bf16* Hs = (bf16*)smem;
  int tid = threadIdx.x;
  int t0 = pair * 2, t1 = t0 + 1;

  uint32_t su0[4][P], st0[4][P];
  gather_issue<P, UM, TM>(TU, TT, idxU, idxT, t0 * 16, tid, su0, st0);
  corr_store<P, UM, TM>(Hs, su0, st0, tid);
  __syncthreads();

  uint32_t su1[4][P], st1[4][P];
  gather_issue<P, UM, TM>(TU, TT, idxU, idxT, t1 * 16, tid, su1, st1);

  compute_tile<P>(smem, BmT, WcT, pw1T, pb1, pw2, Zall, wbuf, m, t0);

  corr_store<P, UM, TM>(Hs, su1, st1, tid);
  __syncthreads();

  compute_tile<P>(smem, BmT, WcT, pw1T, pb1, pw2, Zall, wbuf, m, t1);
}

// ---------------- all 5 metapaths in one launch ----------------------------
// grid = 2560: bid>>9 = m, bid&511 = tile-pair
__global__ __launch_bounds__(512) void fused_all(
    const ushort* __restrict__ EU, const ushort* __restrict__ EI,
    const float* __restrict__ emb_a1, const float* __restrict__ emb_a2,
    const float* __restrict__ emb_a3,
    const int* __restrict__ UI,    const int* __restrict__ IU,
    const int* __restrict__ UIUI,  const int* __restrict__ IUIU,
    const int* __restrict__ UIAI1, const int* __restrict__ IAIU1,
    const int* __restrict__ UIAI2, const int* __restrict__ IAIU2,
    const int* __restrict__ UIAI3, const int* __restrict__ IAIU3,
    const bf16* __restrict__ BmT, const bf16* __restrict__ WcT,
    const bf16* __restrict__ pw1T,
    const float* __restrict__ pb1, const float* __restrict__ pw2,
    bf16* __restrict__ Zall, float* __restrict__ wbuf)
{
  extern __shared__ char smem[];
  int bid = blockIdx.x;
  int m = bid >> 9, pair = bid & 511;
  if (m == 0) {
    pipeline_body<2, 0, 0>(smem, EU, EI, nullptr, nullptr,
                           EI, EU, nullptr, nullptr,
                           UI, IU, BmT, WcT, pw1T, pb1, pw2,
                           Zall, wbuf, 0, pair);
  } else if (m == 1) {
    pipeline_body<4, 0, 0>(smem, EU, EI, EU, EI,
                           EI, EU, EI, EU,
                           UIUI, IUIU,
                           BmT + (size_t)1 * 49152, WcT + (size_t)1 * 49152,
                           pw1T, pb1, pw2, Zall, wbuf, 1, pair);
  } else {
    const float* at = (m == 2) ? emb_a1 : (m == 3) ? emb_a2 : emb_a3;
    const int* iu_ = (m == 2) ? UIAI1 : (m == 3) ? UIAI2 : UIAI3;
    const int* it_ = (m == 2) ? IAIU1 : (m == 3) ? IAIU2 : IAIU3;
    pipeline_body<4, 4, 2>(smem, EU, EI, at, EI,
                           EI, at, EI, EU,
                           iu_, it_,
                           BmT + (size_t)m * 49152, WcT + (size_t)m * 49152,
                           pw1T, pb1, pw2, Zall, wbuf, m, pair);
  }
}

// ---------------- fused tail: beta softmax + pout + final MLP --------------
__global__ __launch_bounds__(512) void fused_tail(
    const bf16* __restrict__ Zall,    // [512*160][128], row b*160+j
    const float* __restrict__ wbuf,   // [512*160]
    const int* __restrict__ UI, const int* __restrict__ IU,
    const float* __restrict__ emb_user, const float* __restrict__ emb_item,
    const float* __restrict__ fw1, const float* __restrict__ fb1,
    const float* __restrict__ fw2, const float* __restrict__ fb2,
    float* __restrict__ out)
{
  __shared__ bf16 Zs[160 * 136];
  __shared__ float wrow[160];
  __shared__ float ph[4][128];
  __shared__ float xs[384];
  __shared__ float sred[16];
  __shared__ float yred[2];

  int b = blockIdx.x, tid = threadIdx.x;
  int lane = tid & 63, wid = tid >> 6;

  {
    const float4* src = (const float4*)(Zall + (size_t)b * 160 * 128);
    float4 v[5];
    #pragma unroll
    for (int i = 0; i < 5; ++i) v[i] = src[i * 512 + tid];
    if (tid < 160) wrow[tid] = wbuf[b * 160 + tid];
    #pragma unroll
    for (int i = 0; i < 5; ++i) {
      int idx = i * 512 + tid;
      int row = idx >> 4, c8 = idx & 15;
      *(float4*)&Zs[row * 136 + c8 * 8] = v[i];
    }
  }
  __syncthreads();

  {
    float v = (tid < 160) ? wrow[tid] : -1e30f;
    #pragma unroll
    for (int off = 32; off; off >>= 1) v = fmaxf(v, __shfl_xor(v, off));
    if (lane == 0) sred[wid] = v;
    __syncthreads();
    if (tid < 64) {
      float mval = (lane < 8) ? sred[lane] : -1e30f;
      #pragma unroll
      for (int off = 4; off; off >>= 1) mval = fmaxf(mval, __shfl_xor(mval, off));
      if (lane == 0) sred[8] = mval;
    }
    __syncthreads();
    float mx = sred[8];
    float ev = (tid < 160) ? __expf(wrow[tid] - mx) : 0.f;
    float s = ev;
    #pragma unroll
    for (int off = 32; off; off >>= 1) s += __shfl_xor(s, off);
    if (lane == 0) sred[wid] = s;
    __syncthreads();
    if (tid < 64) {
      float sval = (lane < 8) ? sred[lane] : 0.f;
      #pragma unroll
      for (int off = 4; off; off >>= 1) sval += __shfl_xor(sval, off);
      if (lane == 0) sred[9] = sval;
    }
    __syncthreads();
    if (tid < 160) wrow[tid] = ev / sred[9];
  }
  __syncthreads();

  {
    int e = tid & 127, q = tid >> 7;
    float acc = 0.f;
    #pragma unroll 4
    for (int j = q * 40; j < q * 40 + 40; ++j)
      acc += wrow[j] * __bfloat162float(Zs[j * 136 + e]);
    ph[q][e] = acc;
  }
  __syncthreads();

  {
    int su = UI[b * 64];
    int ti = IU[b * 64];
    if (tid < 128) {
      xs[256 + tid] = ph[0][tid] + ph[1][tid] + ph[2][tid] + ph[3][tid];
    } else if (tid < 256) {
      xs[tid - 128] = emb_user[(size_t)su * 128 + (tid - 128)];
    } else if (tid < 384) {
      xs[tid - 128] = emb_item[(size_t)ti * 128 + (tid - 256)];
    }
  }
  __syncthreads();

  {
    int o = tid & 127, q = tid >> 7;
    float acc = 0.f;
    #pragma unroll 4
    for (int i = q * 96; i < q * 96 + 96; ++i)
      acc += xs[i] * fw1[(size_t)i * 128 + o];
    __syncthreads();
    ph[q][o] = acc;
  }
  __syncthreads();
  if (tid < 128) {
    float y = fmaxf(ph[0][tid] + ph[1][tid] + ph[2][tid] + ph[3][tid] + fb1[tid],
                    0.0f) * fw2[tid];
    #pragma unroll
    for (int off = 32; off; off >>= 1) y += __shfl_down(y, off);
    if ((tid & 63) == 0) yred[tid >> 6] = y;
  }
  __syncthreads();
  if (tid == 0) {
    float s = yred[0] + yred[1] + fb2[0];
    out[b] = 1.0f / (1.0f + expf(-s));
  }
}

// ---------------------------------------------------------------------------
extern "C" void kernel_launch(void* const* d_in, const int* in_sizes, int n_in,
                              void* d_out, int out_size, void* d_ws, size_t ws_size,
                              hipStream_t stream)
{
  const int* UI    = (const int*)d_in[0];
  const int* IU    = (const int*)d_in[1];
  const int* UIUI  = (const int*)d_in[2];
  const int* IUIU  = (const int*)d_in[3];
  const int* UIAI1 = (const int*)d_in[4];
  const int* IAIU1 = (const int*)d_in[5];
  const int* UIAI2 = (const int*)d_in[6];
  const int* IAIU2 = (const int*)d_in[7];
  const int* UIAI3 = (const int*)d_in[8];
  const int* IAIU3 = (const int*)d_in[9];
  const float* emb_user = (const float*)d_in[10];
  const float* emb_item = (const float*)d_in[11];
  const float* emb_a1   = (const float*)d_in[12];
  const float* emb_a2   = (const float*)d_in[13];
  const float* emb_a3   = (const float*)d_in[14];
  const float* Wt  = (const float*)d_in[15];
  const float* Ws  = (const float*)d_in[16];
  const float* Wc  = (const float*)d_in[17];
  const float* pw1 = (const float*)d_in[18];
  const float* pb1 = (const float*)d_in[19];
  const float* pw2 = (const float*)d_in[20];
  const float* fw1 = (const float*)d_in[21];
  const float* fb1 = (const float*)d_in[22];
  const float* fw2 = (const float*)d_in[23];
  const float* fb2 = (const float*)d_in[24];
  float* out = (float*)d_out;

  // ---- workspace carve (bytes) ----
  char* wsb = (char*)d_ws;
  bf16*   BmT  = (bf16*)wsb;                          // 491,520 B
  bf16*   WcT  = (bf16*)(wsb + 491520);               // 491,520 B
  bf16*   pw1T = (bf16*)(wsb + 983040);               //  32,768 B
  bf16*   Zall = (bf16*)(wsb + 1015808);              // 20,971,520 B
  float*  wbuf = (float*)(wsb + 21987328);            //    327,680 B
  ushort* EU16 = (ushort*)(wsb + 22315008);           // 25,600,256 B
  ushort* EI16 = (ushort*)(wsb + 47915264);           // 25,600,256 B

  int n4 = (100001 * 128) / 4;
  conv_emb<<<8192, 256, 0, stream>>>(emb_user, emb_item, EU16, EI16, n4);
  prep_all<<<1264, 256, 0, stream>>>(Ws, Wt, Wc, pw1, BmT, WcT, pw1T);

  // dyn LDS (PP=7): Hs 30464 + Ss 12544 + Al 768 + wred 512 = 44288 B
  fused_all<<<2560, 512, 44288, stream>>>(
      EU16, EI16, emb_a1, emb_a2, emb_a3,
      UI, IU, UIUI, IUIU, UIAI1, IAIU1, UIAI2, IAIU2, UIAI3, IAIU3,
      BmT, WcT, pw1T, pb1, pw2, Zall, wbuf);

  fused_tail<<<512, 512, 0, stream>>>(Zall, wbuf,
                                      UI, IU, emb_user, emb_item,
                                      fw1, fb1, fw2, fb2, out);
}

// Round 10
// 203.233 us; speedup vs baseline: 1.1104x; 1.0579x over previous
//
#include <hip/hip_runtime.h>
#include <hip/hip_bf16.h>
#include <cstdint>
#include <cstddef>

// ---------------------------------------------------------------------------
// GraphHINGE, round 9: best-of composition.
//  - f32 embedding gathers straight from input tables (R6 path; conv_emb
//    deleted — R7 measured bf16 tables as a net loss).
//  - R6/R7 validated fused_all body: 16-node tiles, 512 thr, MFMA phases,
//    butterfly softmax, static-indexed Hbar, 3 barriers + phase-5 w-fold.
//  - Lean tail (no w-GEMM).
// ---------------------------------------------------------------------------

typedef __hip_bfloat16 bf16;
typedef __attribute__((ext_vector_type(8))) short  bfrag;   // 8 bf16 (4 VGPR)
typedef __attribute__((ext_vector_type(4))) float  ffrag;   // 4 f32 acc

__device__ __forceinline__ float bflo(uint32_t u) { return __uint_as_float(u << 16); }
__device__ __forceinline__ float bfhi(uint32_t u) { return __uint_as_float(u & 0xffff0000u); }
__device__ __forceinline__ float bfs(unsigned short s) {
  return __uint_as_float(((uint32_t)s) << 16);
}
__device__ __forceinline__ uint16_t f2bfu(float x) {
  bf16 h = __float2bfloat16(x);
  return *(uint16_t*)&h;
}
__device__ __forceinline__ uint32_t pk2(float lo, float hi) {
  return (uint32_t)f2bfu(lo) | ((uint32_t)f2bfu(hi) << 16);
}

// ---------------- merged prep: BmatT + WcT + pw1T --------------------------
__global__ __launch_bounds__(256) void prep_all(
    const float* __restrict__ Ws, const float* __restrict__ Wt,
    const float* __restrict__ Wc, const float* __restrict__ pw1,
    bf16* __restrict__ BmT, bf16* __restrict__ WcT, bf16* __restrict__ pw1T)
{
  int bid = blockIdx.x;
  int tid = threadIdx.x;
  if (bid < 240) {
    int mh = bid >> 4;   // m*3+h
    int g  = bid & 15;
    int m = mh / 3, h = mh % 3;
    const float* ws = Ws + (size_t)mh * 16384;
    const float* wt = Wt + (size_t)mh * 16384;
    int e = tid & 127, half = tid >> 7;
    __shared__ float wtl[2][128];
    for (int ep0 = g * 8; ep0 < g * 8 + 8; ep0 += 2) {
      int ep = ep0 + half;
      wtl[half][e] = wt[ep * 128 + e];
      __syncthreads();
      float acc = 0.f;
      #pragma unroll 4
      for (int o = 0; o < 128; ++o) acc += ws[e * 128 + o] * wtl[half][o];
      BmT[((size_t)(m * 384 + h * 128 + e)) * 128 + ep] = __float2bfloat16(acc);
      __syncthreads();
    }
  } else if (bid < 1200) {
    int idx = (bid - 240) * 256 + tid;   // < 5*128*384
    int he = idx % 384, mo = idx / 384;
    int m = mo >> 7, o = mo & 127;
    WcT[idx] = __float2bfloat16(Wc[((size_t)m * 384 + he) * 128 + o]);
  } else {
    int idx = (bid - 1200) * 256 + tid;  // < 16384
    int o = idx >> 7, k = idx & 127;
    pw1T[idx] = __float2bfloat16(pw1[(size_t)k * 128 + o]);
  }
}

// ---------------- fused per-metapath body (16 nodes, 512 threads) ----------
template <int P>
__device__ __forceinline__ void metapath_body(
    char* smem,
    const float* __restrict__ Tu0, const float* __restrict__ Tu1,
    const float* __restrict__ Tu2, const float* __restrict__ Tu3,
    const float* __restrict__ Tt0, const float* __restrict__ Tt1,
    const float* __restrict__ Tt2, const float* __restrict__ Tt3,
    const int* __restrict__ idxU, const int* __restrict__ idxT,
    const bf16* __restrict__ BmT,    // [384][128] (this metapath)
    const bf16* __restrict__ WcT,    // [128][384]
    const bf16* __restrict__ pw1T,   // [128][128] (o-major)
    const float* __restrict__ pb1, const float* __restrict__ pw2,
    bf16* __restrict__ Zall, float* __restrict__ wbuf, int m, int tile)
{
  constexpr int PP = 2 * P - 1;
  constexpr int NS = PP * 136;       // node stride in Hs (bf16)
  bf16* Hs = (bf16*)smem;                          // [16][PP][136]
  bf16* Ss = Hs + 16 * NS;                         // [16][392] (S, then Hbar)
  bf16* Al = Ss + 16 * 392;                        // [16][3][8] alpha
  float* wred = (float*)(Al + 16 * 24);            // [8][16]

  int tid = threadIdx.x;
  int lane = tid & 63, wid = tid >> 6;
  int l15 = lane & 15, l4 = lane >> 4;
  int n0 = tile * 16;

  // ---- phase 1: gather (all loads hoisted) + cross-correlate -> Hs ----
  {
    const float* TU[4] = {Tu0, Tu1, Tu2, Tu3};
    const float* TT[4] = {Tt0, Tt1, Tt2, Tt3};
    int e = tid & 127;
    float su[4][P], st[4][P];
    #pragma unroll
    for (int g = 0; g < 4; ++g) {
      int n = n0 + g * 4 + (tid >> 7);
      #pragma unroll
      for (int p = 0; p < P; ++p) {
        su[g][p] = TU[p][(size_t)idxU[n * P + p] * 128 + e];
        st[g][p] = TT[p][(size_t)idxT[n * P + p] * 128 + e];
      }
    }
    #pragma unroll
    for (int g = 0; g < 4; ++g) {
      int ln = g * 4 + (tid >> 7);
      bf16* Hn = &Hs[ln * NS + e];
      #pragma unroll
      for (int k = 0; k < PP; ++k) {
        float acc = 0.f;
        #pragma unroll
        for (int i = 0; i < P; ++i) {
          int j = k + i - (P - 1);
          if (j >= 0 && j < P) acc += su[g][j] * st[g][i];
        }
        Hn[k * 136] = __float2bfloat16(acc);
      }
    }
  }
  __syncthreads();

  // ---- phase 2: S = H0 @ BmatT : M=16, N=384, K=128 (8 waves x 3 frags) ---
  {
    bfrag a[4];
    #pragma unroll
    for (int kk = 0; kk < 4; ++kk)
      a[kk] = *(const bfrag*)&Hs[l15 * NS + kk * 32 + 8 * l4];   // H0 row
    #pragma unroll
    for (int f = 0; f < 3; ++f) {
      int col = wid * 48 + f * 16 + l15;
      ffrag acc = {0.f, 0.f, 0.f, 0.f};
      #pragma unroll
      for (int kk = 0; kk < 4; ++kk) {
        bfrag b = *(const bfrag*)&BmT[(size_t)col * 128 + kk * 32 + 8 * l4];
        acc = __builtin_amdgcn_mfma_f32_16x16x32_bf16(a[kk], b, acc, 0, 0, 0);
      }
      #pragma unroll
      for (int r = 0; r < 4; ++r) {
        int node = 4 * l4 + r;
        Ss[node * 392 + col] = __float2bfloat16(acc[r]);
      }
    }
  }
  __syncthreads();

  // ---- phase 3: logits (MFMA, 2 nodes/wave) -> butterfly softmax ->
  //      alpha(LDS) -> Hbar (static VALU). All within-wave, no barriers. ----
  {
    int nd0 = wid * 2, nd1 = nd0 + 1;
    bool hi = (l15 >= 8);
    int nodeA = hi ? nd1 : nd0;
    int r15 = hi ? (l15 - 8) : l15;               // 0..7
    int ah = (r15 < 3) ? r15 : 2;                 // junk-row clamp
    int bp = (r15 < PP) ? r15 : (PP - 1);         // junk-col clamp
    ffrag lacc = {0.f, 0.f, 0.f, 0.f};
    #pragma unroll
    for (int kk = 0; kk < 4; ++kk) {
      bfrag av = *(const bfrag*)&Ss[nodeA * 392 + ah * 128 + kk * 32 + 8 * l4];
      bfrag bv = *(const bfrag*)&Hs[nodeA * NS + bp * 136 + kk * 32 + 8 * l4];
      lacc = __builtin_amdgcn_mfma_f32_16x16x32_bf16(av, bv, lacc, 0, 0, 0);
    }
    bool val = ((l4 == 0) && !hi && (l15 < PP)) ||
               ((l4 == 2) &&  hi && (r15 < PP));
    float lg0 = val ? lacc[0] * 5.0f : -1e30f;    // /T1
    float lg1 = val ? lacc[1] * 5.0f : -1e30f;
    float lg2 = val ? lacc[2] * 5.0f : -1e30f;
    float m0 = lg0, m1 = lg1, m2 = lg2;
    #pragma unroll
    for (int d = 1; d < 8; d <<= 1) {
      m0 = fmaxf(m0, __shfl_xor(m0, d));
      m1 = fmaxf(m1, __shfl_xor(m1, d));
      m2 = fmaxf(m2, __shfl_xor(m2, d));
    }
    float e0 = val ? __expf(lg0 - m0) : 0.f;
    float e1 = val ? __expf(lg1 - m1) : 0.f;
    float e2 = val ? __expf(lg2 - m2) : 0.f;
    float s0 = e0, s1 = e1, s2 = e2;
    #pragma unroll
    for (int d = 1; d < 8; d <<= 1) {
      s0 += __shfl_xor(s0, d);
      s1 += __shfl_xor(s1, d);
      s2 += __shfl_xor(s2, d);
    }
    if (val) {
      bf16* Aln = Al + nodeA * 24;
      Aln[r15]      = __float2bfloat16(e0 / s0);
      Aln[8 + r15]  = __float2bfloat16(e1 / s1);
      Aln[16 + r15] = __float2bfloat16(e2 / s2);
    }

    // Hbar[node][h*128+e] = sum_p alpha[h][p] * H[p][e]
    int node = tid >> 5, q = tid & 31;
    bfrag al0 = *(const bfrag*)&Al[node * 24];
    bfrag al1 = *(const bfrag*)&Al[node * 24 + 8];
    bfrag al2 = *(const bfrag*)&Al[node * 24 + 16];
    #pragma unroll
    for (int j = 0; j < 2; ++j) {
      int e2i = 4 * q + 2 * j;
      float a00 = 0.f, a01 = 0.f, a10 = 0.f, a11 = 0.f, a20 = 0.f, a21 = 0.f;
      #pragma unroll
      for (int pp = 0; pp < PP; ++pp) {
        uint32_t hv = *(const uint32_t*)&Hs[node * NS + pp * 136 + e2i];
        float lo = bflo(hv), hh = bfhi(hv);
        float f0 = bfs((unsigned short)al0[pp]);
        float f1 = bfs((unsigned short)al1[pp]);
        float f2 = bfs((unsigned short)al2[pp]);
        a00 += f0 * lo; a01 += f0 * hh;
        a10 += f1 * lo; a11 += f1 * hh;
        a20 += f2 * lo; a21 += f2 * hh;
      }
      *(uint32_t*)&Ss[node * 392 +       e2i] = pk2(a00, a01);
      *(uint32_t*)&Ss[node * 392 + 128 + e2i] = pk2(a10, a11);
      *(uint32_t*)&Ss[node * 392 + 256 + e2i] = pk2(a20, a21);
    }
  }
  __syncthreads();

  // ---- phase 4: Z = Hbar @ WcT / 3, write Zall + stage Z in LDS ----------
  bf16* Zs = Hs;   // Hs free after phase 3
  {
    bfrag a[12];
    #pragma unroll
    for (int kk = 0; kk < 12; ++kk)
      a[kk] = *(const bfrag*)&Ss[l15 * 392 + kk * 32 + 8 * l4];
    int col = wid * 16 + l15;
    ffrag acc = {0.f, 0.f, 0.f, 0.f};
    #pragma unroll
    for (int kk = 0; kk < 12; ++kk) {
      bfrag b = *(const bfrag*)&WcT[(size_t)col * 384 + kk * 32 + 8 * l4];
      acc = __builtin_amdgcn_mfma_f32_16x16x32_bf16(a[kk], b, acc, 0, 0, 0);
    }
    #pragma unroll
    for (int r = 0; r < 4; ++r) {
      int node = 4 * l4 + r;
      int gn = n0 + node;
      int crow = (((gn >> 5) * 5 + m) << 5) + (gn & 31);
      bf16 zb = __float2bfloat16(acc[r] * (1.0f / 3.0f));
      Zall[(size_t)crow * 128 + col] = zb;
      Zs[node * 136 + col] = zb;
    }
  }
  __syncthreads();

  // ---- phase 5: w[node] = 5 * sum_col tanh((Z@pw1)[col]+pb1)*pw2 ---------
  {
    bfrag a5[4];
    #pragma unroll
    for (int kk = 0; kk < 4; ++kk)
      a5[kk] = *(const bfrag*)&Zs[l15 * 136 + kk * 32 + 8 * l4];
    int col = wid * 16 + l15;
    ffrag acc5 = {0.f, 0.f, 0.f, 0.f};
    #pragma unroll
    for (int kk = 0; kk < 4; ++kk) {
      bfrag b = *(const bfrag*)&pw1T[(size_t)col * 128 + kk * 32 + 8 * l4];
      acc5 = __builtin_amdgcn_mfma_f32_16x16x32_bf16(a5[kk], b, acc5, 0, 0, 0);
    }
    float bias = pb1[col], w2 = pw2[col];
    float part[4];
    #pragma unroll
    for (int r = 0; r < 4; ++r) part[r] = tanhf(acc5[r] + bias) * w2;
    #pragma unroll
    for (int d = 1; d < 16; d <<= 1) {
      #pragma unroll
      for (int r = 0; r < 4; ++r) part[r] += __shfl_xor(part[r], d);
    }
    if (l15 == 0) {
      #pragma unroll
      for (int r = 0; r < 4; ++r) wred[wid * 16 + 4 * l4 + r] = part[r];
    }
  }
  __syncthreads();
  if (tid < 16) {
    float s = 0.f;
    #pragma unroll
    for (int w = 0; w < 8; ++w) s += wred[w * 16 + tid];
    int gn = n0 + tid;
    int crow = (((gn >> 5) * 5 + m) << 5) + (gn & 31);
    wbuf[crow] = s * 5.0f;   // /T2
  }
}

// ---------------- all 5 metapaths in one launch ----------------------------
// grid = 5120: bid>>10 = m, bid&1023 = tile
__global__ __launch_bounds__(512) void fused_all(
    const float* __restrict__ emb_user, const float* __restrict__ emb_item,
    const float* __restrict__ emb_a1, const float* __restrict__ emb_a2,
    const float* __restrict__ emb_a3,
    const int* __restrict__ UI,    const int* __restrict__ IU,
    const int* __restrict__ UIUI,  const int* __restrict__ IUIU,
    const int* __restrict__ UIAI1, const int* __restrict__ IAIU1,
    const int* __restrict__ UIAI2, const int* __restrict__ IAIU2,
    const int* __restrict__ UIAI3, const int* __restrict__ IAIU3,
    const bf16* __restrict__ BmT, const bf16* __restrict__ WcT,
    const bf16* __restrict__ pw1T,
    const float* __restrict__ pb1, const float* __restrict__ pw2,
    bf16* __restrict__ Zall, float* __restrict__ wbuf)
{
  extern __shared__ char smem[];
  int bid = blockIdx.x;
  int m = bid >> 10, tile = bid & 1023;
  if (m == 0) {
    metapath_body<2>(smem, emb_user, emb_item, nullptr, nullptr,
                     emb_item, emb_user, nullptr, nullptr,
                     UI, IU, BmT, WcT, pw1T, pb1, pw2,
                     Zall, wbuf, 0, tile);
  } else {
    const float* u2 = (m == 1) ? emb_user : (m == 2) ? emb_a1
                    : (m == 3) ? emb_a2 : emb_a3;
    const int* iu_ = (m == 1) ? UIUI : (m == 2) ? UIAI1
                   : (m == 3) ? UIAI2 : UIAI3;
    const int* it_ = (m == 1) ? IUIU : (m == 2) ? IAIU1
                   : (m == 3) ? IAIU2 : IAIU3;
    metapath_body<4>(smem, emb_user, emb_item, u2, emb_item,
                     emb_item, u2, emb_item, emb_user,
                     iu_, it_,
                     BmT + (size_t)m * 49152, WcT + (size_t)m * 49152,
                     pw1T, pb1, pw2, Zall, wbuf, m, tile);
  }
}

// ---------------- fused tail: beta softmax + pout + final MLP --------------
__global__ __launch_bounds__(512) void fused_tail(
    const bf16* __restrict__ Zall,    // [512*160][128], row b*160+j
    const float* __restrict__ wbuf,   // [512*160]
    const int* __restrict__ UI, const int* __restrict__ IU,
    const float* __restrict__ emb_user, const float* __restrict__ emb_item,
    const float* __restrict__ fw1, const float* __restrict__ fb1,
    const float* __restrict__ fw2, const float* __restrict__ fb2,
    float* __restrict__ out)
{
  __shared__ bf16 Zs[160 * 136];
  __shared__ float wrow[160];
  __shared__ float ph[4][128];
  __shared__ float xs[384];
  __shared__ float sred[16];
  __shared__ float yred[2];

  int b = blockIdx.x, tid = threadIdx.x;
  int lane = tid & 63, wid = tid >> 6;

  {
    const float4* src = (const float4*)(Zall + (size_t)b * 160 * 128);
    float4 v[5];
    #pragma unroll
    for (int i = 0; i < 5; ++i) v[i] = src[i * 512 + tid];
    if (tid < 160) wrow[tid] = wbuf[b * 160 + tid];
    #pragma unroll
    for (int i = 0; i < 5; ++i) {
      int idx = i * 512 + tid;
      int row = idx >> 4, c8 = idx & 15;
      *(float4*)&Zs[row * 136 + c8 * 8] = v[i];
    }
  }
  __syncthreads();

  {
    float v = (tid < 160) ? wrow[tid] : -1e30f;
    #pragma unroll
    for (int off = 32; off; off >>= 1) v = fmaxf(v, __shfl_xor(v, off));
    if (lane == 0) sred[wid] = v;
    __syncthreads();
    if (tid < 64) {
      float mval = (lane < 8) ? sred[lane] : -1e30f;
      #pragma unroll
      for (int off = 4; off; off >>= 1) mval = fmaxf(mval, __shfl_xor(mval, off));
      if (lane == 0) sred[8] = mval;
    }
    __syncthreads();
    float mx = sred[8];
    float ev = (tid < 160) ? __expf(wrow[tid] - mx) : 0.f;
    float s = ev;
    #pragma unroll
    for (int off = 32; off; off >>= 1) s += __shfl_xor(s, off);
    if (lane == 0) sred[wid] = s;
    __syncthreads();
    if (tid < 64) {
      float sval = (lane < 8) ? sred[lane] : 0.f;
      #pragma unroll
      for (int off = 4; off; off >>= 1) sval += __shfl_xor(sval, off);
      if (lane == 0) sred[9] = sval;
    }
    __syncthreads();
    if (tid < 160) wrow[tid] = ev / sred[9];
  }
  __syncthreads();

  {
    int e = tid & 127, q = tid >> 7;
    float acc = 0.f;
    #pragma unroll 4
    for (int j = q * 40; j < q * 40 + 40; ++j)
      acc += wrow[j] * __bfloat162float(Zs[j * 136 + e]);
    ph[q][e] = acc;
  }
  __syncthreads();

  {
    int su = UI[b * 64];
    int ti = IU[b * 64];
    if (tid < 128) {
      xs[256 + tid] = ph[0][tid] + ph[1][tid] + ph[2][tid] + ph[3][tid];
    } else if (tid < 256) {
      xs[tid - 128] = emb_user[(size_t)su * 128 + (tid - 128)];
    } else if (tid < 384) {
      xs[tid - 128] = emb_item[(size_t)ti * 128 + (tid - 256)];
    }
  }
  __syncthreads();

  {
    int o = tid & 127, q = tid >> 7;
    float acc = 0.f;
    #pragma unroll 4
    for (int i = q * 96; i < q * 96 + 96; ++i)
      acc += xs[i] * fw1[(size_t)i * 128 + o];
    __syncthreads();
    ph[q][o] = acc;
  }
  __syncthreads();
  if (tid < 128) {
    float y = fmaxf(ph[0][tid] + ph[1][tid] + ph[2][tid] + ph[3][tid] + fb1[tid],
                    0.0f) * fw2[tid];
    #pragma unroll
    for (int off = 32; off; off >>= 1) y += __shfl_down(y, off);
    if ((tid & 63) == 0) yred[tid >> 6] = y;
  }
  __syncthreads();
  if (tid == 0) {
    float s = yred[0] + yred[1] + fb2[0];
    out[b] = 1.0f / (1.0f + expf(-s));
  }
}

// ---------------------------------------------------------------------------
extern "C" void kernel_launch(void* const* d_in, const int* in_sizes, int n_in,
                              void* d_out, int out_size, void* d_ws, size_t ws_size,
                              hipStream_t stream)
{
  const int* UI    = (const int*)d_in[0];
  const int* IU    = (const int*)d_in[1];
  const int* UIUI  = (const int*)d_in[2];
  const int* IUIU  = (const int*)d_in[3];
  const int* UIAI1 = (const int*)d_in[4];
  const int* IAIU1 = (const int*)d_in[5];
  const int* UIAI2 = (const int*)d_in[6];
  const int* IAIU2 = (const int*)d_in[7];
  const int* UIAI3 = (const int*)d_in[8];
  const int* IAIU3 = (const int*)d_in[9];
  const float* emb_user = (const float*)d_in[10];
  const float* emb_item = (const float*)d_in[11];
  const float* emb_a1   = (const float*)d_in[12];
  const float* emb_a2   = (const float*)d_in[13];
  const float* emb_a3   = (const float*)d_in[14];
  const float* Wt  = (const float*)d_in[15];
  const float* Ws  = (const float*)d_in[16];
  const float* Wc  = (const float*)d_in[17];
  const float* pw1 = (const float*)d_in[18];
  const float* pb1 = (const float*)d_in[19];
  const float* pw2 = (const float*)d_in[20];
  const float* fw1 = (const float*)d_in[21];
  const float* fb1 = (const float*)d_in[22];
  const float* fw2 = (const float*)d_in[23];
  const float* fb2 = (const float*)d_in[24];
  float* out = (float*)d_out;

  // ---- workspace carve (bytes) ----
  char* wsb = (char*)d_ws;
  bf16*   BmT  = (bf16*)wsb;                          // 491,520 B
  bf16*   WcT  = (bf16*)(wsb + 491520);               // 491,520 B
  bf16*   pw1T = (bf16*)(wsb + 983040);               //  32,768 B
  bf16*   Zall = (bf16*)(wsb + 1015808);              // 20,971,520 B
  float*  wbuf = (float*)(wsb + 21987328);            //    327,680 B

  prep_all<<<1264, 256, 0, stream>>>(Ws, Wt, Wc, pw1, BmT, WcT, pw1T);

  // dyn LDS (PP=7): Hs 30464 + Ss 12544 + Al 768 + wred 512 = 44288 B
  fused_all<<<5120, 512, 44288, stream>>>(
      emb_user, emb_item, emb_a1, emb_a2, emb_a3,
      UI, IU, UIUI, IUIU, UIAI1, IAIU1, UIAI2, IAIU2, UIAI3, IAIU3,
      BmT, WcT, pw1T, pb1, pw2, Zall, wbuf);

  fused_tail<<<512, 512, 0, stream>>>(Zall, wbuf,
                                      UI, IU, emb_user, emb_item,
                                      fw1, fb1, fw2, fb2, out);
}

// Round 11
// 201.270 us; speedup vs baseline: 1.1213x; 1.0098x over previous
//
#include <hip/hip_runtime.h>
#include <hip/hip_bf16.h>
#include <cstdint>
#include <cstddef>

// ---------------------------------------------------------------------------
// GraphHINGE, round 10: R9 body + float2 gather (1 wave-request per 512B row
// instead of 2). Tests whether the gather plateau is TA request-rate-bound.
// ---------------------------------------------------------------------------

typedef __hip_bfloat16 bf16;
typedef __attribute__((ext_vector_type(8))) short  bfrag;   // 8 bf16 (4 VGPR)
typedef __attribute__((ext_vector_type(4))) float  ffrag;   // 4 f32 acc

__device__ __forceinline__ float bflo(uint32_t u) { return __uint_as_float(u << 16); }
__device__ __forceinline__ float bfhi(uint32_t u) { return __uint_as_float(u & 0xffff0000u); }
__device__ __forceinline__ float bfs(unsigned short s) {
  return __uint_as_float(((uint32_t)s) << 16);
}
__device__ __forceinline__ uint16_t f2bfu(float x) {
  bf16 h = __float2bfloat16(x);
  return *(uint16_t*)&h;
}
__device__ __forceinline__ uint32_t pk2(float lo, float hi) {
  return (uint32_t)f2bfu(lo) | ((uint32_t)f2bfu(hi) << 16);
}

// ---------------- merged prep: BmatT + WcT + pw1T --------------------------
__global__ __launch_bounds__(256) void prep_all(
    const float* __restrict__ Ws, const float* __restrict__ Wt,
    const float* __restrict__ Wc, const float* __restrict__ pw1,
    bf16* __restrict__ BmT, bf16* __restrict__ WcT, bf16* __restrict__ pw1T)
{
  int bid = blockIdx.x;
  int tid = threadIdx.x;
  if (bid < 240) {
    int mh = bid >> 4;   // m*3+h
    int g  = bid & 15;
    int m = mh / 3, h = mh % 3;
    const float* ws = Ws + (size_t)mh * 16384;
    const float* wt = Wt + (size_t)mh * 16384;
    int e = tid & 127, half = tid >> 7;
    __shared__ float wtl[2][128];
    for (int ep0 = g * 8; ep0 < g * 8 + 8; ep0 += 2) {
      int ep = ep0 + half;
      wtl[half][e] = wt[ep * 128 + e];
      __syncthreads();
      float acc = 0.f;
      #pragma unroll 4
      for (int o = 0; o < 128; ++o) acc += ws[e * 128 + o] * wtl[half][o];
      BmT[((size_t)(m * 384 + h * 128 + e)) * 128 + ep] = __float2bfloat16(acc);
      __syncthreads();
    }
  } else if (bid < 1200) {
    int idx = (bid - 240) * 256 + tid;   // < 5*128*384
    int he = idx % 384, mo = idx / 384;
    int m = mo >> 7, o = mo & 127;
    WcT[idx] = __float2bfloat16(Wc[((size_t)m * 384 + he) * 128 + o]);
  } else {
    int idx = (bid - 1200) * 256 + tid;  // < 16384
    int o = idx >> 7, k = idx & 127;
    pw1T[idx] = __float2bfloat16(pw1[(size_t)k * 128 + o]);
  }
}

// ---------------- fused per-metapath body (16 nodes, 512 threads) ----------
template <int P>
__device__ __forceinline__ void metapath_body(
    char* smem,
    const float* __restrict__ Tu0, const float* __restrict__ Tu1,
    const float* __restrict__ Tu2, const float* __restrict__ Tu3,
    const float* __restrict__ Tt0, const float* __restrict__ Tt1,
    const float* __restrict__ Tt2, const float* __restrict__ Tt3,
    const int* __restrict__ idxU, const int* __restrict__ idxT,
    const bf16* __restrict__ BmT,    // [384][128] (this metapath)
    const bf16* __restrict__ WcT,    // [128][384]
    const bf16* __restrict__ pw1T,   // [128][128] (o-major)
    const float* __restrict__ pb1, const float* __restrict__ pw2,
    bf16* __restrict__ Zall, float* __restrict__ wbuf, int m, int tile)
{
  constexpr int PP = 2 * P - 1;
  constexpr int NS = PP * 136;       // node stride in Hs (bf16)
  bf16* Hs = (bf16*)smem;                          // [16][PP][136]
  bf16* Ss = Hs + 16 * NS;                         // [16][392] (S, then Hbar)
  bf16* Al = Ss + 16 * 392;                        // [16][3][8] alpha
  float* wred = (float*)(Al + 16 * 24);            // [8][16]

  int tid = threadIdx.x;
  int lane = tid & 63, wid = tid >> 6;
  int l15 = lane & 15, l4 = lane >> 4;
  int n0 = tile * 16;

  // ---- phase 1: float2 gather (one wave-request per 512B row) + corr ----
  {
    const float* TU[4] = {Tu0, Tu1, Tu2, Tu3};
    const float* TT[4] = {Tt0, Tt1, Tt2, Tt3};
    int e2 = (tid & 63) * 2;           // 0,2,..,126: lane covers 2 elements
    float2 su[2][P], st[2][P];
    #pragma unroll
    for (int g = 0; g < 2; ++g) {
      int n = n0 + g * 8 + wid;        // wave-uniform node -> scalar idx loads
      #pragma unroll
      for (int p = 0; p < P; ++p) {
        su[g][p] = *(const float2*)&TU[p][(size_t)idxU[n * P + p] * 128 + e2];
        st[g][p] = *(const float2*)&TT[p][(size_t)idxT[n * P + p] * 128 + e2];
      }
    }
    #pragma unroll
    for (int g = 0; g < 2; ++g) {
      int ln = g * 8 + wid;
      bf16* Hn = &Hs[ln * NS + e2];
      #pragma unroll
      for (int k = 0; k < PP; ++k) {
        float ax = 0.f, ay = 0.f;
        #pragma unroll
        for (int i = 0; i < P; ++i) {
          int j = k + i - (P - 1);
          if (j >= 0 && j < P) {
            ax += su[g][j].x * st[g][i].x;
            ay += su[g][j].y * st[g][i].y;
          }
        }
        *(uint32_t*)&Hn[k * 136] = pk2(ax, ay);
      }
    }
  }
  __syncthreads();

  // ---- phase 2: S = H0 @ BmatT : M=16, N=384, K=128 (8 waves x 3 frags) ---
  {
    bfrag a[4];
    #pragma unroll
    for (int kk = 0; kk < 4; ++kk)
      a[kk] = *(const bfrag*)&Hs[l15 * NS + kk * 32 + 8 * l4];   // H0 row
    #pragma unroll
    for (int f = 0; f < 3; ++f) {
      int col = wid * 48 + f * 16 + l15;
      ffrag acc = {0.f, 0.f, 0.f, 0.f};
      #pragma unroll
      for (int kk = 0; kk < 4; ++kk) {
        bfrag b = *(const bfrag*)&BmT[(size_t)col * 128 + kk * 32 + 8 * l4];
        acc = __builtin_amdgcn_mfma_f32_16x16x32_bf16(a[kk], b, acc, 0, 0, 0);
      }
      #pragma unroll
      for (int r = 0; r < 4; ++r) {
        int node = 4 * l4 + r;
        Ss[node * 392 + col] = __float2bfloat16(acc[r]);
      }
    }
  }
  __syncthreads();

  // ---- phase 3: logits (MFMA, 2 nodes/wave) -> butterfly softmax ->
  //      alpha(LDS) -> Hbar (static VALU). All within-wave, no barriers. ----
  {
    int nd0 = wid * 2, nd1 = nd0 + 1;
    bool hi = (l15 >= 8);
    int nodeA = hi ? nd1 : nd0;
    int r15 = hi ? (l15 - 8) : l15;               // 0..7
    int ah = (r15 < 3) ? r15 : 2;                 // junk-row clamp
    int bp = (r15 < PP) ? r15 : (PP - 1);         // junk-col clamp
    ffrag lacc = {0.f, 0.f, 0.f, 0.f};
    #pragma unroll
    for (int kk = 0; kk < 4; ++kk) {
      bfrag av = *(const bfrag*)&Ss[nodeA * 392 + ah * 128 + kk * 32 + 8 * l4];
      bfrag bv = *(const bfrag*)&Hs[nodeA * NS + bp * 136 + kk * 32 + 8 * l4];
      lacc = __builtin_amdgcn_mfma_f32_16x16x32_bf16(av, bv, lacc, 0, 0, 0);
    }
    bool val = ((l4 == 0) && !hi && (l15 < PP)) ||
               ((l4 == 2) &&  hi && (r15 < PP));
    float lg0 = val ? lacc[0] * 5.0f : -1e30f;    // /T1
    float lg1 = val ? lacc[1] * 5.0f : -1e30f;
    float lg2 = val ? lacc[2] * 5.0f : -1e30f;
    float m0 = lg0, m1 = lg1, m2 = lg2;
    #pragma unroll
    for (int d = 1; d < 8; d <<= 1) {
      m0 = fmaxf(m0, __shfl_xor(m0, d));
      m1 = fmaxf(m1, __shfl_xor(m1, d));
      m2 = fmaxf(m2, __shfl_xor(m2, d));
    }
    float e0 = val ? __expf(lg0 - m0) : 0.f;
    float e1 = val ? __expf(lg1 - m1) : 0.f;
    float e2 = val ? __expf(lg2 - m2) : 0.f;
    float s0 = e0, s1 = e1, s2 = e2;
    #pragma unroll
    for (int d = 1; d < 8; d <<= 1) {
      s0 += __shfl_xor(s0, d);
      s1 += __shfl_xor(s1, d);
      s2 += __shfl_xor(s2, d);
    }
    if (val) {
      bf16* Aln = Al + nodeA * 24;
      Aln[r15]      = __float2bfloat16(e0 / s0);
      Aln[8 + r15]  = __float2bfloat16(e1 / s1);
      Aln[16 + r15] = __float2bfloat16(e2 / s2);
    }

    // Hbar[node][h*128+e] = sum_p alpha[h][p] * H[p][e]
    int node = tid >> 5, q = tid & 31;
    bfrag al0 = *(const bfrag*)&Al[node * 24];
    bfrag al1 = *(const bfrag*)&Al[node * 24 + 8];
    bfrag al2 = *(const bfrag*)&Al[node * 24 + 16];
    #pragma unroll
    for (int j = 0; j < 2; ++j) {
      int e2i = 4 * q + 2 * j;
      float a00 = 0.f, a01 = 0.f, a10 = 0.f, a11 = 0.f, a20 = 0.f, a21 = 0.f;
      #pragma unroll
      for (int pp = 0; pp < PP; ++pp) {
        uint32_t hv = *(const uint32_t*)&Hs[node * NS + pp * 136 + e2i];
        float lo = bflo(hv), hh = bfhi(hv);
        float f0 = bfs((unsigned short)al0[pp]);
        float f1 = bfs((unsigned short)al1[pp]);
        float f2 = bfs((unsigned short)al2[pp]);
        a00 += f0 * lo; a01 += f0 * hh;
        a10 += f1 * lo; a11 += f1 * hh;
        a20 += f2 * lo; a21 += f2 * hh;
      }
      *(uint32_t*)&Ss[node * 392 +       e2i] = pk2(a00, a01);
      *(uint32_t*)&Ss[node * 392 + 128 + e2i] = pk2(a10, a11);
      *(uint32_t*)&Ss[node * 392 + 256 + e2i] = pk2(a20, a21);
    }
  }
  __syncthreads();

  // ---- phase 4: Z = Hbar @ WcT / 3, write Zall + stage Z in LDS ----------
  bf16* Zs = Hs;   // Hs free after phase 3
  {
    bfrag a[12];
    #pragma unroll
    for (int kk = 0; kk < 12; ++kk)
      a[kk] = *(const bfrag*)&Ss[l15 * 392 + kk * 32 + 8 * l4];
    int col = wid * 16 + l15;
    ffrag acc = {0.f, 0.f, 0.f, 0.f};
    #pragma unroll
    for (int kk = 0; kk < 12; ++kk) {
      bfrag b = *(const bfrag*)&WcT[(size_t)col * 384 + kk * 32 + 8 * l4];
      acc = __builtin_amdgcn_mfma_f32_16x16x32_bf16(a[kk], b, acc, 0, 0, 0);
    }
    #pragma unroll
    for (int r = 0; r < 4; ++r) {
      int node = 4 * l4 + r;
      int gn = n0 + node;
      int crow = (((gn >> 5) * 5 + m) << 5) + (gn & 31);
      bf16 zb = __float2bfloat16(acc[r] * (1.0f / 3.0f));
      Zall[(size_t)crow * 128 + col] = zb;
      Zs[node * 136 + col] = zb;
    }
  }
  __syncthreads();

  // ---- phase 5: w[node] = 5 * sum_col tanh((Z@pw1)[col]+pb1)*pw2 ---------
  {
    bfrag a5[4];
    #pragma unroll
    for (int kk = 0; kk < 4; ++kk)
      a5[kk] = *(const bfrag*)&Zs[l15 * 136 + kk * 32 + 8 * l4];
    int col = wid * 16 + l15;
    ffrag acc5 = {0.f, 0.f, 0.f, 0.f};
    #pragma unroll
    for (int kk = 0; kk < 4; ++kk) {
      bfrag b = *(const bfrag*)&pw1T[(size_t)col * 128 + kk * 32 + 8 * l4];
      acc5 = __builtin_amdgcn_mfma_f32_16x16x32_bf16(a5[kk], b, acc5, 0, 0, 0);
    }
    float bias = pb1[col], w2 = pw2[col];
    float part[4];
    #pragma unroll
    for (int r = 0; r < 4; ++r) part[r] = tanhf(acc5[r] + bias) * w2;
    #pragma unroll
    for (int d = 1; d < 16; d <<= 1) {
      #pragma unroll
      for (int r = 0; r < 4; ++r) part[r] += __shfl_xor(part[r], d);
    }
    if (l15 == 0) {
      #pragma unroll
      for (int r = 0; r < 4; ++r) wred[wid * 16 + 4 * l4 + r] = part[r];
    }
  }
  __syncthreads();
  if (tid < 16) {
    float s = 0.f;
    #pragma unroll
    for (int w = 0; w < 8; ++w) s += wred[w * 16 + tid];
    int gn = n0 + tid;
    int crow = (((gn >> 5) * 5 + m) << 5) + (gn & 31);
    wbuf[crow] = s * 5.0f;   // /T2
  }
}

// ---------------- all 5 metapaths in one launch ----------------------------
// grid = 5120: bid>>10 = m, bid&1023 = tile
__global__ __launch_bounds__(512) void fused_all(
    const float* __restrict__ emb_user, const float* __restrict__ emb_item,
    const float* __restrict__ emb_a1, const float* __restrict__ emb_a2,
    const float* __restrict__ emb_a3,
    const int* __restrict__ UI,    const int* __restrict__ IU,
    const int* __restrict__ UIUI,  const int* __restrict__ IUIU,
    const int* __restrict__ UIAI1, const int* __restrict__ IAIU1,
    const int* __restrict__ UIAI2, const int* __restrict__ IAIU2,
    const int* __restrict__ UIAI3, const int* __restrict__ IAIU3,
    const bf16* __restrict__ BmT, const bf16* __restrict__ WcT,
    const bf16* __restrict__ pw1T,
    const float* __restrict__ pb1, const float* __restrict__ pw2,
    bf16* __restrict__ Zall, float* __restrict__ wbuf)
{
  extern __shared__ char smem[];
  int bid = blockIdx.x;
  int m = bid >> 10, tile = bid & 1023;
  if (m == 0) {
    metapath_body<2>(smem, emb_user, emb_item, nullptr, nullptr,
                     emb_item, emb_user, nullptr, nullptr,
                     UI, IU, BmT, WcT, pw1T, pb1, pw2,
                     Zall, wbuf, 0, tile);
  } else {
    const float* u2 = (m == 1) ? emb_user : (m == 2) ? emb_a1
                    : (m == 3) ? emb_a2 : emb_a3;
    const int* iu_ = (m == 1) ? UIUI : (m == 2) ? UIAI1
                   : (m == 3) ? UIAI2 : UIAI3;
    const int* it_ = (m == 1) ? IUIU : (m == 2) ? IAIU1
                   : (m == 3) ? IAIU2 : IAIU3;
    metapath_body<4>(smem, emb_user, emb_item, u2, emb_item,
                     emb_item, u2, emb_item, emb_user,
                     iu_, it_,
                     BmT + (size_t)m * 49152, WcT + (size_t)m * 49152,
                     pw1T, pb1, pw2, Zall, wbuf, m, tile);
  }
}

// ---------------- fused tail: beta softmax + pout + final MLP --------------
__global__ __launch_bounds__(512) void fused_tail(
    const bf16* __restrict__ Zall,    // [512*160][128], row b*160+j
    const float* __restrict__ wbuf,   // [512*160]
    const int* __restrict__ UI, const int* __restrict__ IU,
    const float* __restrict__ emb_user, const float* __restrict__ emb_item,
    const float* __restrict__ fw1, const float* __restrict__ fb1,
    const float* __restrict__ fw2, const float* __restrict__ fb2,
    float* __restrict__ out)
{
  __shared__ bf16 Zs[160 * 136];
  __shared__ float wrow[160];
  __shared__ float ph[4][128];
  __shared__ float xs[384];
  __shared__ float sred[16];
  __shared__ float yred[2];

  int b = blockIdx.x, tid = threadIdx.x;
  int lane = tid & 63, wid = tid >> 6;

  {
    const float4* src = (const float4*)(Zall + (size_t)b * 160 * 128);
    float4 v[5];
    #pragma unroll
    for (int i = 0; i < 5; ++i) v[i] = src[i * 512 + tid];
    if (tid < 160) wrow[tid] = wbuf[b * 160 + tid];
    #pragma unroll
    for (int i = 0; i < 5; ++i) {
      int idx = i * 512 + tid;
      int row = idx >> 4, c8 = idx & 15;
      *(float4*)&Zs[row * 136 + c8 * 8] = v[i];
    }
  }
  __syncthreads();

  {
    float v = (tid < 160) ? wrow[tid] : -1e30f;
    #pragma unroll
    for (int off = 32; off; off >>= 1) v = fmaxf(v, __shfl_xor(v, off));
    if (lane == 0) sred[wid] = v;
    __syncthreads();
    if (tid < 64) {
      float mval = (lane < 8) ? sred[lane] : -1e30f;
      #pragma unroll
      for (int off = 4; off; off >>= 1) mval = fmaxf(mval, __shfl_xor(mval, off));
      if (lane == 0) sred[8] = mval;
    }
    __syncthreads();
    float mx = sred[8];
    float ev = (tid < 160) ? __expf(wrow[tid] - mx) : 0.f;
    float s = ev;
    #pragma unroll
    for (int off = 32; off; off >>= 1) s += __shfl_xor(s, off);
    if (lane == 0) sred[wid] = s;
    __syncthreads();
    if (tid < 64) {
      float sval = (lane < 8) ? sred[lane] : 0.f;
      #pragma unroll
      for (int off = 4; off; off >>= 1) sval += __shfl_xor(sval, off);
      if (lane == 0) sred[9] = sval;
    }
    __syncthreads();
    if (tid < 160) wrow[tid] = ev / sred[9];
  }
  __syncthreads();

  {
    int e = tid & 127, q = tid >> 7;
    float acc = 0.f;
    #pragma unroll 4
    for (int j = q * 40; j < q * 40 + 40; ++j)
      acc += wrow[j] * __bfloat162float(Zs[j * 136 + e]);
    ph[q][e] = acc;
  }
  __syncthreads();

  {
    int su = UI[b * 64];
    int ti = IU[b * 64];
    if (tid < 128) {
      xs[256 + tid] = ph[0][tid] + ph[1][tid] + ph[2][tid] + ph[3][tid];
    } else if (tid < 256) {
      xs[tid - 128] = emb_user[(size_t)su * 128 + (tid - 128)];
    } else if (tid < 384) {
      xs[tid - 128] = emb_item[(size_t)ti * 128 + (tid - 256)];
    }
  }
  __syncthreads();

  {
    int o = tid & 127, q = tid >> 7;
    float acc = 0.f;
    #pragma unroll 4
    for (int i = q * 96; i < q * 96 + 96; ++i)
      acc += xs[i] * fw1[(size_t)i * 128 + o];
    __syncthreads();
    ph[q][o] = acc;
  }
  __syncthreads();
  if (tid < 128) {
    float y = fmaxf(ph[0][tid] + ph[1][tid] + ph[2][tid] + ph[3][tid] + fb1[tid],
                    0.0f) * fw2[tid];
    #pragma unroll
    for (int off = 32; off; off >>= 1) y += __shfl_down(y, off);
    if ((tid & 63) == 0) yred[tid >> 6] = y;
  }
  __syncthreads();
  if (tid == 0) {
    float s = yred[0] + yred[1] + fb2[0];
    out[b] = 1.0f / (1.0f + expf(-s));
  }
}

// ---------------------------------------------------------------------------
extern "C" void kernel_launch(void* const* d_in, const int* in_sizes, int n_in,
                              void* d_out, int out_size, void* d_ws, size_t ws_size,
                              hipStream_t stream)
{
  const int* UI    = (const int*)d_in[0];
  const int* IU    = (const int*)d_in[1];
  const int* UIUI  = (const int*)d_in[2];
  const int* IUIU  = (const int*)d_in[3];
  const int* UIAI1 = (const int*)d_in[4];
  const int* IAIU1 = (const int*)d_in[5];
  const int* UIAI2 = (const int*)d_in[6];
  const int* IAIU2 = (const int*)d_in[7];
  const int* UIAI3 = (const int*)d_in[8];
  const int* IAIU3 = (const int*)d_in[9];
  const float* emb_user = (const float*)d_in[10];
  const float* emb_item = (const float*)d_in[11];
  const float* emb_a1   = (const float*)d_in[12];
  const float* emb_a2   = (const float*)d_in[13];
  const float* emb_a3   = (const float*)d_in[14];
  const float* Wt  = (const float*)d_in[15];
  const float* Ws  = (const float*)d_in[16];
  const float* Wc  = (const float*)d_in[17];
  const float* pw1 = (const float*)d_in[18];
  const float* pb1 = (const float*)d_in[19];
  const float* pw2 = (const float*)d_in[20];
  const float* fw1 = (const float*)d_in[21];
  const float* fb1 = (const float*)d_in[22];
  const float* fw2 = (const float*)d_in[23];
  const float* fb2 = (const float*)d_in[24];
  float* out = (float*)d_out;

  // ---- workspace carve (bytes) ----
  char* wsb = (char*)d_ws;
  bf16*   BmT  = (bf16*)wsb;                          // 491,520 B
  bf16*   WcT  = (bf16*)(wsb + 491520);               // 491,520 B
  bf16*   pw1T = (bf16*)(wsb + 983040);               //  32,768 B
  bf16*   Zall = (bf16*)(wsb + 1015808);              // 20,971,520 B
  float*  wbuf = (float*)(wsb + 21987328);            //    327,680 B

  prep_all<<<1264, 256, 0, stream>>>(Ws, Wt, Wc, pw1, BmT, WcT, pw1T);

  // dyn LDS (PP=7): Hs 30464 + Ss 12544 + Al 768 + wred 512 = 44288 B
  fused_all<<<5120, 512, 44288, stream>>>(
      emb_user, emb_item, emb_a1, emb_a2, emb_a3,
      UI, IU, UIUI, IUIU, UIAI1, IAIU1, UIAI2, IAIU2, UIAI3, IAIU3,
      BmT, WcT, pw1T, pb1, pw2, Zall, wbuf);

  fused_tail<<<512, 512, 0, stream>>>(Zall, wbuf,
                                      UI, IU, emb_user, emb_item,
                                      fw1, fb1, fw2, fb2, out);
}